// Round 1
// baseline (279.977 us; speedup 1.0000x reference)
//
#include <hip/hip_runtime.h>
#include <cstdint>

constexpr int D = 256;     // D_IN == D_OUT
constexpr int TM = 128;    // block m-tile; block o-tile = 256 (full)

typedef __bf16 bf16x8 __attribute__((ext_vector_type(8)));
typedef float  f32x4  __attribute__((ext_vector_type(4)));

// ---- prep 1: W2 = W (fp32), b2 = b ------------------------------------
__global__ void prep_copy(const float* __restrict__ W, const float* __restrict__ b,
                          float* __restrict__ W2, float* __restrict__ b2) {
    int i = blockIdx.x * 256 + threadIdx.x;
    W2[i] = W[i];
    if (blockIdx.x == 0) b2[threadIdx.x] = b[threadIdx.x];
}

// ---- prep 2: per edge: W2[dst,:] += W[src,:]; b2[dst] += b[src] --------
__global__ void prep_edges(const int* __restrict__ em, int E,
                           const float* __restrict__ W, const float* __restrict__ b,
                           float* __restrict__ W2, float* __restrict__ b2) {
    int e = blockIdx.x;
    int k = threadIdx.x;
    int dst = em[e];
    int src = em[E + e];
    atomicAdd(&W2[dst * D + k], W[src * D + k]);
    if (k == 0) atomicAdd(&b2[dst], b[src]);
}

// ---- prep 3: W2 fp32 -> frag-order bf16 hi/lo -------------------------
// Layout per k-32 chunk kc: [o16b(16)][lane(64)][j(8)]  (8192 elems = 16 KB)
// B-frag (16x16x32): lane holds B[o = o16b*16 + (lane&15)][k = kc*32 + (lane>>4)*8 + j]
__global__ void prep_convert(const float* __restrict__ W2, ushort* __restrict__ Wh,
                             ushort* __restrict__ Wl) {
    int i = blockIdx.x * 256 + threadIdx.x;   // i = o*256 + k
    int o = i >> 8, k = i & 255;
    float x = W2[i];
    uint32_t u  = __float_as_uint(x);
    uint32_t hu = u & 0xFFFF0000u;            // hi = truncate to bf16
    float r = x - __uint_as_float(hu);        // exact residual
    uint32_t ru = __float_as_uint(r);
    uint32_t lu = ru + 0x7FFFu + ((ru >> 16) & 1u);   // RNE to bf16
    int kc = k >> 5, kk = k & 31, q = kk >> 3, j = kk & 7;
    int o16b = o >> 4;
    int lane = (o & 15) + 16 * q;
    int idx = kc * 8192 + (o16b * 64 + lane) * 8 + j;
    Wh[idx] = (ushort)(hu >> 16);
    Wl[idx] = (ushort)(lu >> 16);
}

// ---- in-register fp32x8 -> bf16 hi/lo (split, RNE on residual) --------
__device__ __forceinline__ void cvt8v(const float4& f0, const float4& f1,
                                      bf16x8& hi, bf16x8& lo) {
    float xs[8] = {f0.x, f0.y, f0.z, f0.w, f1.x, f1.y, f1.z, f1.w};
    uint32_t h[8], l[8];
    #pragma unroll
    for (int j = 0; j < 8; ++j) {
        uint32_t u  = __float_as_uint(xs[j]);
        uint32_t hu = u & 0xFFFF0000u;
        h[j] = hu;
        float r = xs[j] - __uint_as_float(hu);
        uint32_t ru = __float_as_uint(r);
        l[j] = ru + 0x7FFFu + ((ru >> 16) & 1u);
    }
    union { uint4 u; bf16x8 v; } ch, cl;
    ch.u = make_uint4((h[0] >> 16) | (h[1] & 0xFFFF0000u),
                      (h[2] >> 16) | (h[3] & 0xFFFF0000u),
                      (h[4] >> 16) | (h[5] & 0xFFFF0000u),
                      (h[6] >> 16) | (h[7] & 0xFFFF0000u));
    cl.u = make_uint4((l[0] >> 16) | (l[1] & 0xFFFF0000u),
                      (l[2] >> 16) | (l[3] & 0xFFFF0000u),
                      (l[4] >> 16) | (l[5] & 0xFFFF0000u),
                      (l[6] >> 16) | (l[7] & 0xFFFF0000u));
    hi = ch.v;
    lo = cl.v;
}

// ---- main: out[m,o] = (x[m,:].W2[o,:] + b2[o]) / bl[m] via split-bf16 MFMA
// Barrier-free / LDS-free: every fragment loaded straight from global in
// frag order. block: 256 thr = 4 waves; tile m-128 x o-256; wave m-128 x o-64.
// W frags: lane-contiguous 16B -> perfectly coalesced dwordx4, L2-resident.
// X frags: per lane 8 contiguous fp32 (two float4); 64B segments, L1-reused
// by the 4 o-waves of the block. fp32->bf16 hi/lo split done in-register.
__global__ __launch_bounds__(256, 2) void resgcn_mfma(
    const float* __restrict__ X, const ushort* __restrict__ Whg,
    const ushort* __restrict__ Wlg, const float* __restrict__ b2,
    const float* __restrict__ blen, float* __restrict__ out, int M)
{
    const int tid  = threadIdx.x;
    const int lane = tid & 63;
    const int wv   = tid >> 6;                 // wave's o-quadrant
    const int m0   = blockIdx.x * TM;

    // A-frag (16x16x32): lane holds A[m = a*16 + (lane&15)][k = kc*32 + (lane>>4)*8 + j]
    const int rlow = lane & 15;
    const int kq   = lane >> 4;                // 0..3

    const float* xbase[8];
    #pragma unroll
    for (int a = 0; a < 8; ++a) {
        int r = m0 + a * 16 + rlow;
        if (r >= M) r = M - 1;                 // tail clamp: real data, stores guarded
        xbase[a] = X + (size_t)r * D + kq * 8;
    }

    // W frag base: idx = kc*8192 + (o16b*64 + lane)*8, o16b = wv*4 + b
    const ushort* whb = Whg + ((wv * 4) * 64 + lane) * 8;
    const ushort* wlb = Wlg + ((wv * 4) * 64 + lane) * 8;

    f32x4 acc[8][4];
    #pragma unroll
    for (int a = 0; a < 8; ++a)
        #pragma unroll
        for (int b = 0; b < 4; ++b) acc[a][b] = (f32x4){0.f, 0.f, 0.f, 0.f};

    #pragma unroll 2
    for (int kc = 0; kc < 8; ++kc) {
        bf16x8 bh[4], bl[4];
        #pragma unroll
        for (int b = 0; b < 4; ++b) {
            bh[b] = *(const bf16x8*)(whb + kc * 8192 + b * 512);
            bl[b] = *(const bf16x8*)(wlb + kc * 8192 + b * 512);
        }
        #pragma unroll
        for (int a = 0; a < 8; ++a) {
            const float* p = xbase[a] + kc * 32;
            float4 f0 = *(const float4*)(p + 0);
            float4 f1 = *(const float4*)(p + 4);
            bf16x8 ah, al;
            cvt8v(f0, f1, ah, al);
            #pragma unroll
            for (int b = 0; b < 4; ++b) {
                acc[a][b] = __builtin_amdgcn_mfma_f32_16x16x32_bf16(ah, bh[b], acc[a][b], 0, 0, 0);
                acc[a][b] = __builtin_amdgcn_mfma_f32_16x16x32_bf16(al, bh[b], acc[a][b], 0, 0, 0);
                acc[a][b] = __builtin_amdgcn_mfma_f32_16x16x32_bf16(ah, bl[b], acc[a][b], 0, 0, 0);
            }
        }
    }

    // epilogue: C/D layout col=lane&15, row=(lane>>4)*4+reg  (m89-verified)
    const int col = lane & 15;
    const int rq  = lane >> 4;
    float bias[4];
    #pragma unroll
    for (int b = 0; b < 4; ++b) bias[b] = b2[(wv * 4 + b) * 16 + col];

    #pragma unroll
    for (int a = 0; a < 8; ++a) {
        #pragma unroll
        for (int r = 0; r < 4; ++r) {
            int m = m0 + a * 16 + rq * 4 + r;
            if (m < M) {
                float inv = 1.0f / blen[m];
                #pragma unroll
                for (int b = 0; b < 4; ++b) {
                    int o = (wv * 4 + b) * 16 + col;
                    out[(size_t)m * D + o] = (acc[a][b][r] + bias[b]) * inv;
                }
            }
        }
    }
}

extern "C" void kernel_launch(void* const* d_in, const int* in_sizes, int n_in,
                              void* d_out, int out_size, void* d_ws, size_t ws_size,
                              hipStream_t stream) {
    (void)n_in; (void)out_size; (void)ws_size;
    const float* X  = (const float*)d_in[0];
    const float* W  = (const float*)d_in[1];
    const float* b  = (const float*)d_in[2];
    const int*   em = (const int*)d_in[3];
    const float* bl = (const float*)d_in[4];
    float* out = (float*)d_out;

    const int M = in_sizes[0] / D;
    const int E = in_sizes[3] / 2;

    float*  W2 = (float*)d_ws;            // 65536 fp32
    float*  b2 = W2 + D * D;              // 256 fp32
    ushort* Wh = (ushort*)(b2 + D);       // 65536 bf16 (16B-aligned offset)
    ushort* Wl = Wh + D * D;              // 65536 bf16

    prep_copy<<<D * D / 256, 256, 0, stream>>>(W, b, W2, b2);
    prep_edges<<<E, D, 0, stream>>>(em, E, W, b, W2, b2);
    prep_convert<<<D * D / 256, 256, 0, stream>>>(W2, Wh, Wl);

    int mblocks = (M + TM - 1) / TM;
    resgcn_mfma<<<mblocks, 256, 0, stream>>>(X, Wh, Wl, b2, bl, out, M);
}

// Round 3
// 224.947 us; speedup vs baseline: 1.2446x; 1.2446x over previous
//
#include <hip/hip_runtime.h>
#include <cstdint>

constexpr int D = 256;     // D_IN == D_OUT
constexpr int TM = 64;     // block m-tile; block o-tile = 256 (full)

typedef __bf16 bf16x8 __attribute__((ext_vector_type(8)));
typedef float  f32x4  __attribute__((ext_vector_type(4)));

// ---- prep 1: W2 = W (fp32), b2 = b ------------------------------------
__global__ void prep_copy(const float* __restrict__ W, const float* __restrict__ b,
                          float* __restrict__ W2, float* __restrict__ b2) {
    int i = blockIdx.x * 256 + threadIdx.x;
    W2[i] = W[i];
    if (blockIdx.x == 0) b2[threadIdx.x] = b[threadIdx.x];
}

// ---- prep 2: per edge: W2[dst,:] += W[src,:]; b2[dst] += b[src] --------
__global__ void prep_edges(const int* __restrict__ em, int E,
                           const float* __restrict__ W, const float* __restrict__ b,
                           float* __restrict__ W2, float* __restrict__ b2) {
    int e = blockIdx.x;
    int k = threadIdx.x;
    int dst = em[e];
    int src = em[E + e];
    atomicAdd(&W2[dst * D + k], W[src * D + k]);
    if (k == 0) atomicAdd(&b2[dst], b[src]);
}

// ---- prep 3: W2 fp32 -> frag-order bf16 hi/lo -------------------------
// Layout per k-32 chunk kc: [o16b(16)][lane(64)][j(8)]  (8192 elems = 16 KB)
// B-frag (16x16x32): lane holds B[o = o16b*16 + (lane&15)][k = kc*32 + (lane>>4)*8 + j]
__global__ void prep_convert(const float* __restrict__ W2, ushort* __restrict__ Wh,
                             ushort* __restrict__ Wl) {
    int i = blockIdx.x * 256 + threadIdx.x;   // i = o*256 + k
    int o = i >> 8, k = i & 255;
    float x = W2[i];
    uint32_t u  = __float_as_uint(x);
    uint32_t hu = u & 0xFFFF0000u;            // hi = truncate to bf16
    float r = x - __uint_as_float(hu);        // exact residual
    uint32_t ru = __float_as_uint(r);
    uint32_t lu = ru + 0x7FFFu + ((ru >> 16) & 1u);   // RNE to bf16
    int kc = k >> 5, kk = k & 31, q = kk >> 3, j = kk & 7;
    int o16b = o >> 4;
    int lane = (o & 15) + 16 * q;
    int idx = kc * 8192 + (o16b * 64 + lane) * 8 + j;
    Wh[idx] = (ushort)(hu >> 16);
    Wl[idx] = (ushort)(lu >> 16);
}

// ---- fp32x8 -> packed bf16 hi/lo uint4s (split, RNE on residual) ------
__device__ __forceinline__ void cvt8(const float4& f0, const float4& f1,
                                     uint4& hi, uint4& lo) {
    float xs[8] = {f0.x, f0.y, f0.z, f0.w, f1.x, f1.y, f1.z, f1.w};
    uint32_t h[8], l[8];
    #pragma unroll
    for (int j = 0; j < 8; ++j) {
        uint32_t u  = __float_as_uint(xs[j]);
        uint32_t hu = u & 0xFFFF0000u;
        h[j] = hu;
        float r = xs[j] - __uint_as_float(hu);
        uint32_t ru = __float_as_uint(r);
        l[j] = ru + 0x7FFFu + ((ru >> 16) & 1u);
    }
    hi = make_uint4((h[0] >> 16) | (h[1] & 0xFFFF0000u),
                    (h[2] >> 16) | (h[3] & 0xFFFF0000u),
                    (h[4] >> 16) | (h[5] & 0xFFFF0000u),
                    (h[6] >> 16) | (h[7] & 0xFFFF0000u));
    lo = make_uint4((l[0] >> 16) | (l[1] & 0xFFFF0000u),
                    (l[2] >> 16) | (l[3] & 0xFFFF0000u),
                    (l[4] >> 16) | (l[5] & 0xFFFF0000u),
                    (l[6] >> 16) | (l[7] & 0xFFFF0000u));
}

// ---- main: out[m,o] = (x[m,:].W2[o,:] + b2[o]) / bl[m] via split-bf16 MFMA
// block: 256 thr = 4 waves; tile m-64 x o-256; wave = m-64 x o-64 (acc 4x4).
// X: LDS-staged (4x cross-wave reuse), double-buffered, ONE barrier per kc
//    at iteration END -- next-chunk global loads issued at iteration TOP so
//    the MFMA phase covers their latency.
// W: direct global per-wave (zero cross-wave reuse -> LDS buys nothing),
//    frag-ordered dwordx4, L2-resident.
__global__ __launch_bounds__(256, 3) void resgcn_mfma(
    const float* __restrict__ X, const ushort* __restrict__ Whg,
    const ushort* __restrict__ Wlg, const float* __restrict__ b2,
    const float* __restrict__ blen, float* __restrict__ out, int M)
{
    __shared__ ushort Xh[2][4][64][8];   // [buf][m16b][lane][j]  8 KB
    __shared__ ushort Xl[2][4][64][8];   //                       8 KB

    const int tid  = threadIdx.x;
    const int lane = tid & 63;
    const int wv   = tid >> 6;                 // wave's o-quadrant
    const int m0   = blockIdx.x * TM;

    // X staging coords: thread covers row sm, 8-float quarter sh of each 32-k chunk
    const int sm = tid >> 2;                   // 0..63
    const int sh = tid & 3;                    // 0..3
    int srow = m0 + sm; if (srow >= M) srow = M - 1;   // clamp: real data, stores guarded
    const float* xrow = X + (size_t)srow * D + sh * 8;
    const int m16b = sm >> 4;
    const int wlane = (sm & 15) + 16 * sh;     // frag lane this thread fills

    // W frag base: idx = kc*8192 + ((wv*4+b)*64 + lane)*8
    const ushort* whb = Whg + ((wv * 4) * 64 + lane) * 8;
    const ushort* wlb = Wlg + ((wv * 4) * 64 + lane) * 8;

    f32x4 acc[4][4];
    #pragma unroll
    for (int a = 0; a < 4; ++a)
        #pragma unroll
        for (int b = 0; b < 4; ++b) acc[a][b] = (f32x4){0.f, 0.f, 0.f, 0.f};

    // ---- prologue: stage chunk 0 into buf 0 ----
    {
        float4 f0 = *(const float4*)(xrow + 0);
        float4 f1 = *(const float4*)(xrow + 4);
        uint4 h, l;
        cvt8(f0, f1, h, l);
        *(uint4*)&Xh[0][m16b][wlane][0] = h;
        *(uint4*)&Xl[0][m16b][wlane][0] = l;
    }
    __syncthreads();

    #pragma unroll 2
    for (int kc = 0; kc < 8; ++kc) {
        const int cur = kc & 1;

        // issue next chunk's X loads early -- MFMA phase covers the latency
        float4 nf0, nf1;
        if (kc < 7) {
            const float* p = xrow + (kc + 1) * 32;
            nf0 = *(const float4*)(p + 0);
            nf1 = *(const float4*)(p + 4);
        }

        // W frags for this chunk (L2-resident, coalesced dwordx4)
        bf16x8 bh[4], bl[4];
        #pragma unroll
        for (int b = 0; b < 4; ++b) {
            bh[b] = *(const bf16x8*)(whb + kc * 8192 + b * 512);
            bl[b] = *(const bf16x8*)(wlb + kc * 8192 + b * 512);
        }

        #pragma unroll
        for (int a = 0; a < 4; ++a) {
            bf16x8 ah = *(const bf16x8*)&Xh[cur][a][lane][0];
            bf16x8 al = *(const bf16x8*)&Xl[cur][a][lane][0];
            #pragma unroll
            for (int b = 0; b < 4; ++b) {
                acc[a][b] = __builtin_amdgcn_mfma_f32_16x16x32_bf16(ah, bh[b], acc[a][b], 0, 0, 0);
                acc[a][b] = __builtin_amdgcn_mfma_f32_16x16x32_bf16(al, bh[b], acc[a][b], 0, 0, 0);
                acc[a][b] = __builtin_amdgcn_mfma_f32_16x16x32_bf16(ah, bl[b], acc[a][b], 0, 0, 0);
            }
        }

        // convert + write next chunk into the other buffer, then one barrier
        if (kc < 7) {
            uint4 h, l;
            cvt8(nf0, nf1, h, l);
            *(uint4*)&Xh[cur ^ 1][m16b][wlane][0] = h;
            *(uint4*)&Xl[cur ^ 1][m16b][wlane][0] = l;
        }
        __syncthreads();
    }

    // epilogue: C/D layout col=lane&15, row=(lane>>4)*4+reg  (m89-verified)
    const int col = lane & 15;
    const int rq  = lane >> 4;
    float bias[4];
    #pragma unroll
    for (int b = 0; b < 4; ++b) bias[b] = b2[(wv * 4 + b) * 16 + col];

    #pragma unroll
    for (int a = 0; a < 4; ++a) {
        #pragma unroll
        for (int r = 0; r < 4; ++r) {
            int m = m0 + a * 16 + rq * 4 + r;
            if (m < M) {
                float inv = 1.0f / blen[m];
                #pragma unroll
                for (int b = 0; b < 4; ++b) {
                    int o = (wv * 4 + b) * 16 + col;
                    out[(size_t)m * D + o] = (acc[a][b][r] + bias[b]) * inv;
                }
            }
        }
    }
}

extern "C" void kernel_launch(void* const* d_in, const int* in_sizes, int n_in,
                              void* d_out, int out_size, void* d_ws, size_t ws_size,
                              hipStream_t stream) {
    (void)n_in; (void)out_size; (void)ws_size;
    const float* X  = (const float*)d_in[0];
    const float* W  = (const float*)d_in[1];
    const float* b  = (const float*)d_in[2];
    const int*   em = (const int*)d_in[3];
    const float* bl = (const float*)d_in[4];
    float* out = (float*)d_out;

    const int M = in_sizes[0] / D;
    const int E = in_sizes[3] / 2;

    float*  W2 = (float*)d_ws;            // 65536 fp32
    float*  b2 = W2 + D * D;              // 256 fp32
    ushort* Wh = (ushort*)(b2 + D);       // 65536 bf16 (16B-aligned offset)
    ushort* Wl = Wh + D * D;              // 65536 bf16

    prep_copy<<<D * D / 256, 256, 0, stream>>>(W, b, W2, b2);
    prep_edges<<<E, D, 0, stream>>>(em, E, W, b, W2, b2);
    prep_convert<<<D * D / 256, 256, 0, stream>>>(W2, Wh, Wl);

    int mblocks = (M + TM - 1) / TM;
    resgcn_mfma<<<mblocks, 256, 0, stream>>>(X, Wh, Wl, b2, bl, out, M);
}

// Round 5
// 219.052 us; speedup vs baseline: 1.2781x; 1.0269x over previous
//
#include <hip/hip_runtime.h>
#include <cstdint>

constexpr int D = 256;     // D_IN == D_OUT
constexpr int TM = 64;     // block m-tile; block o-tile = 256 (full)

typedef __bf16 bf16x8 __attribute__((ext_vector_type(8)));
typedef float  f32x4  __attribute__((ext_vector_type(4)));

// ---- prep 1: W2 = W (fp32), b2 = b ------------------------------------
__global__ void prep_copy(const float* __restrict__ W, const float* __restrict__ b,
                          float* __restrict__ W2, float* __restrict__ b2) {
    int i = blockIdx.x * 256 + threadIdx.x;
    W2[i] = W[i];
    if (blockIdx.x == 0) b2[threadIdx.x] = b[threadIdx.x];
}

// ---- prep 2: per edge: W2[dst,:] += W[src,:]; b2[dst] += b[src] --------
__global__ void prep_edges(const int* __restrict__ em, int E,
                           const float* __restrict__ W, const float* __restrict__ b,
                           float* __restrict__ W2, float* __restrict__ b2) {
    int e = blockIdx.x;
    int k = threadIdx.x;
    int dst = em[e];
    int src = em[E + e];
    atomicAdd(&W2[dst * D + k], W[src * D + k]);
    if (k == 0) atomicAdd(&b2[dst], b[src]);
}

// ---- prep 3: W2 fp32 -> frag-order bf16 hi/lo -------------------------
// Layout per k-32 chunk kc: [o16b(16)][lane(64)][j(8)]  (8192 elems = 16 KB)
// B-frag (16x16x32): lane holds B[o = o16b*16 + (lane&15)][k = kc*32 + (lane>>4)*8 + j]
__global__ void prep_convert(const float* __restrict__ W2, ushort* __restrict__ Wh,
                             ushort* __restrict__ Wl) {
    int i = blockIdx.x * 256 + threadIdx.x;   // i = o*256 + k
    int o = i >> 8, k = i & 255;
    float x = W2[i];
    uint32_t u  = __float_as_uint(x);
    uint32_t hu = u & 0xFFFF0000u;            // hi = truncate to bf16
    float r = x - __uint_as_float(hu);        // exact residual
    uint32_t ru = __float_as_uint(r);
    uint32_t lu = ru + 0x7FFFu + ((ru >> 16) & 1u);   // RNE to bf16
    int kc = k >> 5, kk = k & 31, q = kk >> 3, j = kk & 7;
    int o16b = o >> 4;
    int lane = (o & 15) + 16 * q;
    int idx = kc * 8192 + (o16b * 64 + lane) * 8 + j;
    Wh[idx] = (ushort)(hu >> 16);
    Wl[idx] = (ushort)(lu >> 16);
}

// ---- fp32x8 -> packed bf16 hi/lo uint4s (split, RNE on residual) ------
__device__ __forceinline__ void cvt8(const float4& f0, const float4& f1,
                                     uint4& hi, uint4& lo) {
    float xs[8] = {f0.x, f0.y, f0.z, f0.w, f1.x, f1.y, f1.z, f1.w};
    uint32_t h[8], l[8];
    #pragma unroll
    for (int j = 0; j < 8; ++j) {
        uint32_t u  = __float_as_uint(xs[j]);
        uint32_t hu = u & 0xFFFF0000u;
        h[j] = hu;
        float r = xs[j] - __uint_as_float(hu);
        uint32_t ru = __float_as_uint(r);
        l[j] = ru + 0x7FFFu + ((ru >> 16) & 1u);
    }
    hi = make_uint4((h[0] >> 16) | (h[1] & 0xFFFF0000u),
                    (h[2] >> 16) | (h[3] & 0xFFFF0000u),
                    (h[4] >> 16) | (h[5] & 0xFFFF0000u),
                    (h[6] >> 16) | (h[7] & 0xFFFF0000u));
    lo = make_uint4((l[0] >> 16) | (l[1] & 0xFFFF0000u),
                    (l[2] >> 16) | (l[3] & 0xFFFF0000u),
                    (l[4] >> 16) | (l[5] & 0xFFFF0000u),
                    (l[6] >> 16) | (l[7] & 0xFFFF0000u));
}

// ---- main: out[m,o] = (x[m,:].W2[o,:] + b2[o]) / bl[m] via split-bf16 MFMA
// block: 256 thr = 4 waves; tile m-64 x o-256; wave = m-64 x o-64 (acc 4x4).
// X: LDS-staged, double-buffered, one barrier per kc.
// W: direct global per-wave, frag-ordered dwordx4, REGISTER double-buffered
//    (ping-pong sets, manual unroll-2) so load->use spans a full iteration.
// Epilogue: acc -> LDS (XOR-swizzled) -> row-dense float4 stores: cuts the
//    store path from 16 partial 64B segments/inst to 8 full lines/inst.
__global__ __launch_bounds__(256, 3) void resgcn_mfma(
    const float* __restrict__ X, const ushort* __restrict__ Whg,
    const ushort* __restrict__ Wlg, const float* __restrict__ b2,
    const float* __restrict__ blen, float* __restrict__ out, int M)
{
    __shared__ __align__(16) unsigned char smem[16384];
    ushort* XhP = (ushort*)smem;          // [2][4][64][8]  8 KB
    ushort* XlP = XhP + 4096;             // [2][4][64][8]  8 KB
    float*  E   = (float*)smem;           // epilogue slice [16][256] f32 16 KB

    const int tid  = threadIdx.x;
    const int lane = tid & 63;
    const int wv   = tid >> 6;                 // wave's o-quadrant
    const int m0   = blockIdx.x * TM;

    // X staging coords: thread covers row sm, 8-float quarter sh of each 32-k chunk
    const int sm = tid >> 2;                   // 0..63
    const int sh = tid & 3;                    // 0..3
    int srow = m0 + sm; if (srow >= M) srow = M - 1;   // clamp: real data, stores guarded
    const float* xrow = X + (size_t)srow * D + sh * 8;
    const int m16b = sm >> 4;
    const int wlane = (sm & 15) + 16 * sh;     // frag lane this thread fills

    // W frag base: idx = kc*8192 + ((wv*4+b)*64 + lane)*8
    const ushort* whb = Whg + ((wv * 4) * 64 + lane) * 8;
    const ushort* wlb = Wlg + ((wv * 4) * 64 + lane) * 8;

#define LOADW(BH, BL, c) do {                                             \
        _Pragma("unroll")                                                 \
        for (int b = 0; b < 4; ++b) {                                     \
            BH[b] = *(const bf16x8*)(whb + (c) * 8192 + b * 512);         \
            BL[b] = *(const bf16x8*)(wlb + (c) * 8192 + b * 512);         \
        } } while (0)

#define DOMFMA(BH, BL, cur) do {                                          \
        _Pragma("unroll")                                                 \
        for (int a = 0; a < 4; ++a) {                                     \
            bf16x8 ah = *(const bf16x8*)(XhP + (((cur)*4 + a)*64 + lane)*8); \
            bf16x8 al = *(const bf16x8*)(XlP + (((cur)*4 + a)*64 + lane)*8); \
            _Pragma("unroll")                                             \
            for (int b = 0; b < 4; ++b) {                                 \
                acc[a][b] = __builtin_amdgcn_mfma_f32_16x16x32_bf16(ah, BH[b], acc[a][b], 0, 0, 0); \
                acc[a][b] = __builtin_amdgcn_mfma_f32_16x16x32_bf16(al, BH[b], acc[a][b], 0, 0, 0); \
                acc[a][b] = __builtin_amdgcn_mfma_f32_16x16x32_bf16(ah, BL[b], acc[a][b], 0, 0, 0); \
            } } } while (0)

#define STAGEX(nf0, nf1, buf) do {                                        \
        uint4 h_, l_;                                                     \
        cvt8(nf0, nf1, h_, l_);                                           \
        *(uint4*)(XhP + (((buf)*4 + m16b)*64 + wlane)*8) = h_;            \
        *(uint4*)(XlP + (((buf)*4 + m16b)*64 + wlane)*8) = l_;            \
    } while (0)

    f32x4 acc[4][4];
    #pragma unroll
    for (int a = 0; a < 4; ++a)
        #pragma unroll
        for (int b = 0; b < 4; ++b) acc[a][b] = (f32x4){0.f, 0.f, 0.f, 0.f};

    bf16x8 bhA[4], blA[4], bhB[4], blB[4];
    LOADW(bhA, blA, 0);

    // ---- prologue: stage chunk 0 into buf 0 ----
    {
        float4 f0 = *(const float4*)(xrow + 0);
        float4 f1 = *(const float4*)(xrow + 4);
        STAGEX(f0, f1, 0);
    }
    __syncthreads();

    #pragma unroll
    for (int kc = 0; kc < 8; kc += 2) {
        // ---- chunk kc (even): consume set A, buf 0; prefetch set B(kc+1)
        {
            const float* p = xrow + (kc + 1) * 32;          // kc+1 <= 7 always
            float4 nf0 = *(const float4*)(p + 0);
            float4 nf1 = *(const float4*)(p + 4);
            LOADW(bhB, blB, kc + 1);
            DOMFMA(bhA, blA, 0);
            STAGEX(nf0, nf1, 1);
            __syncthreads();
        }
        // ---- chunk kc+1 (odd): consume set B, buf 1; prefetch set A(kc+2)
        {
            float4 nf0, nf1;
            if (kc + 2 < 8) {
                const float* p = xrow + (kc + 2) * 32;
                nf0 = *(const float4*)(p + 0);
                nf1 = *(const float4*)(p + 4);
                LOADW(bhA, blA, kc + 2);
            }
            DOMFMA(bhB, blB, 1);
            if (kc + 2 < 8) STAGEX(nf0, nf1, 0);
            __syncthreads();
        }
    }
    // loop-end barrier: all X ds_reads complete -> smem reusable as E

    // ---- epilogue: LDS-transposed float4 stores --------------------------
    // C/D layout col=lane&15, row=(lane>>4)*4+reg  (m89-verified)
    const int col = lane & 15;
    const int rq  = lane >> 4;
    float bias[4];
    #pragma unroll
    for (int b = 0; b < 4; ++b) bias[b] = b2[(wv * 4 + b) * 16 + col];

    #pragma unroll
    for (int a = 0; a < 4; ++a) {
        if (a) __syncthreads();            // protect E reuse across slices
        // write phase: slice rows 0..15 = local m (a*16 + row); swizzle ^(row&7)<<2
        #pragma unroll
        for (int r = 0; r < 4; ++r) {
            int row = rq * 4 + r;
            int sw  = (row & 7) << 2;
            #pragma unroll
            for (int b = 0; b < 4; ++b) {
                int o = wv * 64 + b * 16 + col;
                E[row * 256 + (o ^ sw)] = acc[a][b][r] + bias[b];
            }
        }
        __syncthreads();
        // read+store phase: wave wv covers rows wv*4..wv*4+3, row-dense
        #pragma unroll
        for (int j = 0; j < 4; ++j) {
            int row = wv * 4 + j;
            int m = m0 + a * 16 + row;
            f32x4 v = *(const f32x4*)&E[row * 256 + ((lane ^ (row & 7)) << 2)];
            if (m < M) {
                float inv = 1.0f / blen[m];
                f32x4 o4 = {v[0] * inv, v[1] * inv, v[2] * inv, v[3] * inv};
                *(f32x4*)&out[(size_t)m * D + lane * 4] = o4;
            }
        }
    }
#undef LOADW
#undef DOMFMA
#undef STAGEX
}

extern "C" void kernel_launch(void* const* d_in, const int* in_sizes, int n_in,
                              void* d_out, int out_size, void* d_ws, size_t ws_size,
                              hipStream_t stream) {
    (void)n_in; (void)out_size; (void)ws_size;
    const float* X  = (const float*)d_in[0];
    const float* W  = (const float*)d_in[1];
    const float* b  = (const float*)d_in[2];
    const int*   em = (const int*)d_in[3];
    const float* bl = (const float*)d_in[4];
    float* out = (float*)d_out;

    const int M = in_sizes[0] / D;
    const int E = in_sizes[3] / 2;

    float*  W2 = (float*)d_ws;            // 65536 fp32
    float*  b2 = W2 + D * D;              // 256 fp32
    ushort* Wh = (ushort*)(b2 + D);       // 65536 bf16 (16B-aligned offset)
    ushort* Wl = Wh + D * D;              // 65536 bf16

    prep_copy<<<D * D / 256, 256, 0, stream>>>(W, b, W2, b2);
    prep_edges<<<E, D, 0, stream>>>(em, E, W, b, W2, b2);
    prep_convert<<<D * D / 256, 256, 0, stream>>>(W2, Wh, Wl);

    int mblocks = (M + TM - 1) / TM;
    resgcn_mfma<<<mblocks, 256, 0, stream>>>(X, Wh, Wl, b2, bl, out, M);
}